// Round 6
// baseline (8779.367 us; speedup 1.0000x reference)
//
#include <hip/hip_runtime.h>
#include <stdint.h>

// R6: rebalanced register budget. R4/R5 post-mortem: total reg demand ~532/lane
// exceeded the 512-reg unified file -> allocator spilled weight arrays to
// scratch (81 GB FETCH/step-loop). R5's inline-asm AGPR pinning also hit an
// uncovered VALU->MFMA hazard (absmax 0.826). Fix: builtins only, demand ~473:
//   - LDS 36 frags/wave (kk7,8 all g; kk6 g3)            = 144 KB  (R4-proven)
//   - static 88 frags/wave (kk0..3 all; kk4,5,6 g0,1)    = 352 regs (AV class
//     -> allocator places most in AGPRs as MFMA-B operands)
//   - streamed 20 frags/wave/step (kk4,5 g2,3; kk6 g2) from pre-packed,
//     per-WG-private d_ws (L2-resident, 80 KB/WG/step, ~0.15us/XCD hidden)
// Anti-LICM: asm-opaque zero index per t-iteration so invariant WLs/stream/
// W_out loads can't be hoisted into registers (would re-bust the budget).
// d_ws: [0,512K) W_out frags (8 KB/WG); [512K, 512K+5.0M) stream packs.

#define B_TOTAL   1024
#define H_DIM     256
#define F_WARM    32
#define F_AUTO    24
#define O_DIM     8
#define T_WARM    512
#define T_TOTAL   1024
#define N4H       1024
#define A_STRIDE  296   // bf16 elems/row: 592 B, 16B-aligned

typedef __attribute__((ext_vector_type(8))) short short8;
typedef __attribute__((ext_vector_type(4))) float float4v;

__device__ __forceinline__ short f2bf(float x) {
    union { float f; uint32_t u; } v; v.f = x;
    uint32_t r = v.u + 0x7FFFu + ((v.u >> 16) & 1u);   // RNE
    return (short)(r >> 16);
}
__device__ __forceinline__ float sigmoid_(float x) {
    const float e = __expf(-x);
    return __builtin_amdgcn_rcpf(1.0f + e);
}
__device__ __forceinline__ float tanh_(float x) {
    const float e = __expf(-2.0f * fabsf(x));
    const float t = (1.0f - e) * __builtin_amdgcn_rcpf(1.0f + e);
    return x >= 0.0f ? t : -t;
}

__global__ __launch_bounds__(256, 1)
void lstm_wg(const float* __restrict__ c0, const float* __restrict__ h0,
             const float* __restrict__ warm, const float* __restrict__ autoin,
             const float* __restrict__ W_ih, const float* __restrict__ W_hh,
             const float* __restrict__ bvec, const float* __restrict__ W_out,
             const float* __restrict__ b_out, float* __restrict__ out,
             unsigned short* __restrict__ ws)
{
    const int tid  = threadIdx.x;
    const int w    = tid >> 6;        // wave 0..3 -> h-units [w*64, w*64+64)
    const int l    = tid & 63;
    const int n16  = l & 15;          // MFMA n (B/D col) / A row (m)
    const int kg   = l >> 4;          // k-group 0..3
    const int row0 = blockIdx.x * 16; // batch rows [row0, row0+16)

    __shared__ __align__(16) short WLs[73728];          // 144 blocks x 1 KB
    __shared__ __align__(16) short Alds[16 * A_STRIDE]; // [x(32) | h(256) | pad]
    __shared__ float biasL[N4H];
    __shared__ float ybuf[16 * O_DIM];

    // ---- LDS weight blocks: kk in {7,8} all gates + (kk=6,g=3) ----
    for (int idx = tid; idx < 73728; idx += 256) {
        const int i    = idx & 7;
        const int lane = (idx >> 3) & 63;
        const int bi   = idx >> 9;
        int kk, g, wq, j;
        if (bi < 128) { kk = 7 + (bi >> 6); const int r6 = bi & 63;
                        g = r6 >> 4; wq = (r6 >> 2) & 3; j = r6 & 3; }
        else          { kk = 6; g = 3; wq = (bi - 128) >> 2; j = (bi - 128) & 3; }
        const int k   = kk * 32 + (lane >> 4) * 8 + i;
        const int col = g * 256 + wq * 64 + j * 16 + (lane & 15);
        const float wv = (k < F_WARM) ? W_ih[k * N4H + col]
                                      : W_hh[(k - F_WARM) * N4H + col];
        WLs[idx] = f2bf(wv);
    }
    for (int e = 0; e < 4; ++e) biasL[tid + e * 256] = bvec[tid + e * 256];

    // ---- W_out MFMA B-frags -> this WG's d_ws region (8 KB) ----
    unsigned short* wsW = ws + (size_t)blockIdx.x * 4096;
    for (int idx = tid; idx < 4096; idx += 256) {
        const int i = idx & 7, lane = (idx >> 3) & 63, kk = idx >> 9;
        const int k = kk * 32 + (lane >> 4) * 8 + i;
        const int n = lane & 15;
        wsW[idx] = (unsigned short)((n < O_DIM) ? f2bf(W_out[k * O_DIM + n]) : (short)0);
    }

    // ---- streamed-frag pack: 20 frags/wave (kk4,5 g2,3 ; kk6 g2), private ----
    // frag f: kk = 4 + (f>>3); g = (f<16) ? 2 + ((f>>2)&1) : 2; j = f&3.
    unsigned short* sPack = ws + 262144;   // after 64 x 8 KB W_out region
    {
        unsigned short* mine =
            sPack + ((size_t)(blockIdx.x * 4 + w) * 20) * 512 + (size_t)l * 8;
        #pragma unroll
        for (int f = 0; f < 20; ++f) {
            const int kk = 4 + (f >> 3);
            const int g  = (f < 16) ? (2 + ((f >> 2) & 1)) : 2;
            const int j  = f & 3;
            const int col = g * 256 + w * 64 + j * 16 + n16;
            short8 v;
            #pragma unroll
            for (int i = 0; i < 8; ++i) {
                const int k = kk * 32 + kg * 8 + i;       // >= 128 -> W_hh
                v[i] = f2bf(W_hh[(k - F_WARM) * N4H + col]);
            }
            *(short8*)(mine + (size_t)f * 512) = v;
        }
    }

    // ---- static register weights (88 frags = 352 regs, AV/AGPR-eligible) ----
    short8 bw03[4][4][4];   // [kk0..3][g][j]
    short8 bw4[2][4];       // kk=4, g0,1
    short8 bw5[2][4];       // kk=5, g0,1
    short8 bw6s[2][4];      // kk=6, g0,1
    #pragma unroll
    for (int g = 0; g < 4; ++g)
        #pragma unroll
        for (int j = 0; j < 4; ++j) {
            const int col = g * 256 + w * 64 + j * 16 + n16;
            #pragma unroll
            for (int kk = 0; kk < 4; ++kk) {
                short8 f;
                #pragma unroll
                for (int i = 0; i < 8; ++i) {
                    const int k = kk * 32 + kg * 8 + i;
                    const float wv = (k < F_WARM) ? W_ih[k * N4H + col]
                                                  : W_hh[(k - F_WARM) * N4H + col];
                    f[i] = f2bf(wv);
                }
                bw03[kk][g][j] = f;
            }
        }
    #pragma unroll
    for (int g = 0; g < 2; ++g)
        #pragma unroll
        for (int j = 0; j < 4; ++j) {
            const int col = g * 256 + w * 64 + j * 16 + n16;
            #pragma unroll
            for (int kk = 4; kk < 7; ++kk) {
                short8 f;
                #pragma unroll
                for (int i = 0; i < 8; ++i) {
                    const int k = kk * 32 + kg * 8 + i;
                    f[i] = f2bf(W_hh[(k - F_WARM) * N4H + col]);
                }
                if (kk == 4) bw4[g][j] = f;
                else if (kk == 5) bw5[g][j] = f;
                else bw6s[g][j] = f;
            }
        }

    const float bout = (w == 0 && n16 < O_DIM) ? b_out[n16] : 0.0f;

    // ---- c state: MFMA C/D layout (col=lane&15, row=kg*4+r) ----
    float creg[4][4];
    #pragma unroll
    for (int j = 0; j < 4; ++j)
        #pragma unroll
        for (int r = 0; r < 4; ++r)
            creg[j][r] = c0[(size_t)(row0 + kg * 4 + r) * H_DIM + (w * 64 + j * 16 + n16)];

    // ---- initial A staging: x_0 (16x32) + h0 (16x256) ----
    #pragma unroll
    for (int e = 0; e < 2; ++e) {
        const int idx = tid + e * 256;
        const int r = idx >> 5, cx = idx & 31;
        Alds[r * A_STRIDE + cx] =
            f2bf(warm[(size_t)(row0 + r) * (T_WARM * F_WARM) + cx]);   // t=0
    }
    #pragma unroll
    for (int e = 0; e < 16; ++e) {
        const int idx = tid + e * 256;
        const int r = idx >> 8, c = idx & 255;
        Alds[r * A_STRIDE + F_WARM + c] = f2bf(h0[(size_t)(row0 + r) * H_DIM + c]);
    }

    const short* abase = &Alds[n16 * A_STRIDE + kg * 8];
    const short* hbase = &Alds[n16 * A_STRIDE + F_WARM + kg * 8];
    const short8* wsW8 = (const short8*)wsW;
    const short8* sBw  = (const short8*)(sPack + ((size_t)(blockIdx.x * 4 + w) * 20) * 512);

    for (int t = 0; t < T_TOTAL; ++t) {
        __syncthreads();                                // A tile ready

        // anti-LICM: opaque zero blocks hoisting of loop-invariant loads
        int lz = 0;
        asm volatile("" : "+v"(lz));

        uint32_t hp[8];                                 // packed bf16 h (16 vals)

        #pragma unroll
        for (int jp = 0; jp < 2; ++jp) {
            // ---- issue the 10 streamed B-frag loads for this pass ----
            // sfrag[2*G+jj]: G0=kk4g2, G1=kk4g3, G2=kk5g2, G3=kk5g3, G4=kk6g2
            short8 sfrag[10];
            #pragma unroll
            for (int G = 0; G < 5; ++G)
                #pragma unroll
                for (int jj = 0; jj < 2; ++jj)
                    sfrag[2 * G + jj] = sBw[(G * 4 + jp * 2 + jj) * 64 + l + lz];

            float4v acc[4][2];
            #pragma unroll
            for (int g = 0; g < 4; ++g)
                #pragma unroll
                for (int jj = 0; jj < 2; ++jj)
                    acc[g][jj] = (float4v){0.f, 0.f, 0.f, 0.f};

            // ---- kk 0..3 (static) ----
            #pragma unroll
            for (int kk = 0; kk < 4; ++kk) {
                const short8 af = *(const short8*)(abase + kk * 32);
                #pragma unroll
                for (int g = 0; g < 4; ++g)
                    #pragma unroll
                    for (int jj = 0; jj < 2; ++jj)
                        acc[g][jj] = __builtin_amdgcn_mfma_f32_16x16x32_bf16(
                                         af, bw03[kk][g][jp * 2 + jj], acc[g][jj], 0, 0, 0);
            }
            // ---- kk=4: g0,1 static; g2,3 streamed ----
            {
                const short8 af = *(const short8*)(abase + 4 * 32);
                #pragma unroll
                for (int jj = 0; jj < 2; ++jj) {
                    acc[0][jj] = __builtin_amdgcn_mfma_f32_16x16x32_bf16(af, bw4[0][jp*2+jj], acc[0][jj], 0, 0, 0);
                    acc[1][jj] = __builtin_amdgcn_mfma_f32_16x16x32_bf16(af, bw4[1][jp*2+jj], acc[1][jj], 0, 0, 0);
                    acc[2][jj] = __builtin_amdgcn_mfma_f32_16x16x32_bf16(af, sfrag[0 + jj],   acc[2][jj], 0, 0, 0);
                    acc[3][jj] = __builtin_amdgcn_mfma_f32_16x16x32_bf16(af, sfrag[2 + jj],   acc[3][jj], 0, 0, 0);
                }
            }
            // ---- kk=5: g0,1 static; g2,3 streamed ----
            {
                const short8 af = *(const short8*)(abase + 5 * 32);
                #pragma unroll
                for (int jj = 0; jj < 2; ++jj) {
                    acc[0][jj] = __builtin_amdgcn_mfma_f32_16x16x32_bf16(af, bw5[0][jp*2+jj], acc[0][jj], 0, 0, 0);
                    acc[1][jj] = __builtin_amdgcn_mfma_f32_16x16x32_bf16(af, bw5[1][jp*2+jj], acc[1][jj], 0, 0, 0);
                    acc[2][jj] = __builtin_amdgcn_mfma_f32_16x16x32_bf16(af, sfrag[4 + jj],   acc[2][jj], 0, 0, 0);
                    acc[3][jj] = __builtin_amdgcn_mfma_f32_16x16x32_bf16(af, sfrag[6 + jj],   acc[3][jj], 0, 0, 0);
                }
            }
            // ---- kk=6: g0,1 static; g2 streamed; g3 LDS ----
            {
                const short8 af = *(const short8*)(abase + 6 * 32);
                #pragma unroll
                for (int jj = 0; jj < 2; ++jj) {
                    acc[0][jj] = __builtin_amdgcn_mfma_f32_16x16x32_bf16(af, bw6s[0][jp*2+jj], acc[0][jj], 0, 0, 0);
                    acc[1][jj] = __builtin_amdgcn_mfma_f32_16x16x32_bf16(af, bw6s[1][jp*2+jj], acc[1][jj], 0, 0, 0);
                    acc[2][jj] = __builtin_amdgcn_mfma_f32_16x16x32_bf16(af, sfrag[8 + jj],    acc[2][jj], 0, 0, 0);
                    const int bi = 128 + w * 4 + (jp * 2 + jj);
                    const short8 bf = *(const short8*)&WLs[bi * 512 + l * 8 + lz];
                    acc[3][jj] = __builtin_amdgcn_mfma_f32_16x16x32_bf16(af, bf, acc[3][jj], 0, 0, 0);
                }
            }
            // ---- kk=7,8 (LDS) ----
            #pragma unroll
            for (int kk = 7; kk < 9; ++kk) {
                const short8 af = *(const short8*)(abase + kk * 32);
                #pragma unroll
                for (int g = 0; g < 4; ++g)
                    #pragma unroll
                    for (int jj = 0; jj < 2; ++jj) {
                        const int bi = (kk - 7) * 64 + g * 16 + w * 4 + (jp * 2 + jj);
                        const short8 bf = *(const short8*)&WLs[bi * 512 + l * 8 + lz];
                        acc[g][jj] = __builtin_amdgcn_mfma_f32_16x16x32_bf16(
                                         af, bf, acc[g][jj], 0, 0, 0);
                    }
            }

            // ---- gates + c/h update for this j-pair ----
            #pragma unroll
            for (int jj = 0; jj < 2; ++jj) {
                const int j  = jp * 2 + jj;
                const int cb = w * 64 + j * 16 + n16;
                const float b0 = biasL[cb];
                const float b1 = biasL[256 + cb];
                const float b2 = biasL[512 + cb];
                const float b3 = biasL[768 + cb];
                uint32_t u0 = 0, u1 = 0;
                #pragma unroll
                for (int r = 0; r < 4; ++r) {
                    const float ig = sigmoid_(acc[0][jj][r] + b0);
                    const float fg = sigmoid_(acc[1][jj][r] + b1);
                    const float gg = tanh_(acc[2][jj][r] + b2);
                    const float og = sigmoid_(acc[3][jj][r] + b3);
                    const float cc = fg * creg[j][r] + ig * gg;
                    creg[j][r] = cc;
                    const float hh = og * tanh_(cc);
                    const uint32_t hb = (uint32_t)(uint16_t)f2bf(hh);
                    if (r == 0) u0 = hb;        else if (r == 1) u0 |= hb << 16;
                    else if (r == 2) u1 = hb;   else             u1 |= hb << 16;
                }
                hp[jp * 4 + jj * 2 + 0] = u0;
                hp[jp * 4 + jj * 2 + 1] = u1;
            }
        }

        __syncthreads();                                // all A reads done

        // ---- write h_t into A-LDS; stage x_{t+1} (non-feedback cols) ----
        #pragma unroll
        for (int jp2 = 0; jp2 < 2; ++jp2)
            #pragma unroll
            for (int jj = 0; jj < 2; ++jj)
                #pragma unroll
                for (int rp = 0; rp < 2; ++rp) {
                    const uint32_t u = hp[jp2 * 4 + jj * 2 + rp];
                    const int col = F_WARM + w * 64 + (jp2 * 2 + jj) * 16 + n16;
                    Alds[(kg * 4 + rp * 2 + 0) * A_STRIDE + col] = (short)(u & 0xFFFF);
                    Alds[(kg * 4 + rp * 2 + 1) * A_STRIDE + col] = (short)(u >> 16);
                }

        if (t + 1 < T_TOTAL) {
            const int tn = t + 1;
            #pragma unroll
            for (int e = 0; e < 2; ++e) {
                const int idx = tid + e * 256;
                const int r = idx >> 5, cx = idx & 31;
                if (tn < T_WARM) {
                    Alds[r * A_STRIDE + cx] =
                        f2bf(warm[(size_t)(row0 + r) * (T_WARM * F_WARM)
                                  + (size_t)tn * F_WARM + cx]);
                } else if (cx < F_AUTO) {
                    Alds[r * A_STRIDE + cx] =
                        f2bf(autoin[(size_t)(row0 + r) * (T_WARM * F_AUTO)
                                    + (size_t)(tn - T_WARM) * F_AUTO + cx]);
                }
            }
        }

        __syncthreads();                                // h region complete

        // ---- wave 0: y_t = h_t @ W_out + b_out via MFMA (frags from d_ws) ----
        if (w == 0) {
            float4v ya = (float4v){bout, bout, bout, bout};
            #pragma unroll
            for (int kk = 0; kk < 8; ++kk)
                ya = __builtin_amdgcn_mfma_f32_16x16x32_bf16(
                         *(const short8*)(hbase + kk * 32), wsW8[kk * 64 + l + lz], ya, 0, 0, 0);
            if (n16 < O_DIM) {
                #pragma unroll
                for (int r = 0; r < 4; ++r) {
                    const int row = kg * 4 + r;
                    const float y = ya[r];
                    ybuf[row * O_DIM + n16] = y;
                    out[(size_t)(row0 + row) * (T_TOTAL * O_DIM)
                        + (size_t)t * O_DIM + n16] = y;
                }
            }
        }

        __syncthreads();                                // ybuf ready

        // ---- feedback: auto-phase x cols [24,32) = y_t ----
        if (t + 1 >= T_WARM && t + 1 < T_TOTAL && tid < 128) {
            const int r = tid >> 3, fo = tid & 7;
            Alds[r * A_STRIDE + F_AUTO + fo] = f2bf(ybuf[r * O_DIM + fo]);
        }
        // loop-top __syncthreads publishes staged A
    }
}

extern "C" void kernel_launch(void* const* d_in, const int* in_sizes, int n_in,
                              void* d_out, int out_size, void* d_ws, size_t ws_size,
                              hipStream_t stream) {
    (void)in_sizes; (void)n_in; (void)out_size; (void)ws_size;
    const float* c0   = (const float*)d_in[0];
    const float* h0   = (const float*)d_in[1];
    const float* warm = (const float*)d_in[2];
    const float* aut  = (const float*)d_in[3];
    const float* Wih  = (const float*)d_in[4];
    const float* Whh  = (const float*)d_in[5];
    const float* b    = (const float*)d_in[6];
    const float* Wout = (const float*)d_in[7];
    const float* bout = (const float*)d_in[8];
    float* out = (float*)d_out;
    // d_ws: [0,512K) W_out frags; [512K, 512K+5.0M) streamed weight packs.
    // Required ws_size ~5.63 MB.
    unsigned short* ws = (unsigned short*)d_ws;

    hipLaunchKernelGGL(lstm_wg, dim3(64), dim3(256), 0, stream,
                       c0, h0, warm, aut, Wih, Whh, b, Wout, bout, out, ws);
}